// Round 1
// baseline (106.435 us; speedup 1.0000x reference)
//
#include <hip/hip_runtime.h>

#define D 128
#define NEG_SLOPE 0.2f

__device__ __forceinline__ float leaky(float x) {
    return (x >= 0.0f) ? x : NEG_SLOPE * x;
}

// Kernel A: one wave (64 threads). Computes s_src[i] = h[i]·W1 and
// s_dst[j] = h[j]·W2, stores to ws[1], ws[2]; zeroes the accumulator ws[0].
__global__ void precompute_kernel(const float* __restrict__ h,
                                  const float* __restrict__ W,
                                  const int* __restrict__ ip,
                                  const int* __restrict__ jp,
                                  float* __restrict__ ws) {
    int lane = threadIdx.x;  // 0..63
    int iv = ip[0];
    int jv = jp[0];
    // each lane covers d = lane and d = lane+64
    float a = h[(long long)iv * D + lane]       * W[lane]
            + h[(long long)iv * D + lane + 64]  * W[lane + 64];
    float c = h[(long long)jv * D + lane]       * W[D + lane]
            + h[(long long)jv * D + lane + 64]  * W[D + lane + 64];
    #pragma unroll
    for (int off = 32; off > 0; off >>= 1) {
        a += __shfl_down(a, off);
        c += __shfl_down(c, off);
    }
    if (lane == 0) {
        ws[0] = 0.0f;   // atomic accumulator for sumneighbors
        ws[1] = a;      // s_src[i]
        ws[2] = c;      // s_dst[j]
    }
}

// Kernel B: scan all edges (2 edges per thread via int4), match src == i,
// compute e = leaky(s_src_i + h[dst]·W2 + b) for matches, atomicAdd into ws[0].
__global__ void scan_edges_kernel(const int4* __restrict__ g2,
                                  long long npairs,
                                  const int* __restrict__ gtail,  // base g ptr for odd tail
                                  long long E,
                                  const float* __restrict__ h,
                                  const float* __restrict__ W,
                                  const int* __restrict__ ip,
                                  const float* __restrict__ bptr,
                                  float* __restrict__ ws) {
    long long idx = (long long)blockIdx.x * blockDim.x + threadIdx.x;
    int iv = ip[0];

    int src0 = -1, dst0 = 0, src1 = -1, dst1 = 0;
    if (idx < npairs) {
        int4 e = g2[idx];
        src0 = e.x; dst0 = e.y;
        src1 = e.z; dst1 = e.w;
    } else if (idx == npairs && (E & 1)) {
        // odd tail edge (not hit for E=3.2M, kept for generality)
        src0 = gtail[2 * (E - 1)];
        dst0 = gtail[2 * (E - 1) + 1];
    }

    bool m0 = (src0 == iv);
    bool m1 = (src1 == iv);
    if (!(m0 || m1)) return;

    // rare path: ~E/N ≈ 32 threads total reach here
    float sSrc = ws[1];
    float b0 = bptr[0];
    const float4* w2 = (const float4*)(W + D);
    float acc = 0.0f;

    if (m0) {
        const float4* hr = (const float4*)(h + (long long)dst0 * D);
        float dot = 0.0f;
        #pragma unroll
        for (int q = 0; q < D / 4; ++q) {
            float4 hv = hr[q];
            float4 wv = w2[q];
            dot += hv.x * wv.x + hv.y * wv.y + hv.z * wv.z + hv.w * wv.w;
        }
        acc += leaky(sSrc + dot + b0);
    }
    if (m1) {
        const float4* hr = (const float4*)(h + (long long)dst1 * D);
        float dot = 0.0f;
        #pragma unroll
        for (int q = 0; q < D / 4; ++q) {
            float4 hv = hr[q];
            float4 wv = w2[q];
            dot += hv.x * wv.x + hv.y * wv.y + hv.z * wv.z + hv.w * wv.w;
        }
        acc += leaky(sSrc + dot + b0);
    }
    atomicAdd(ws, acc);
}

// Kernel C: out[0] = leaky(s_src_i + s_dst_j + b) / sumneighbors
__global__ void finalize_kernel(const float* __restrict__ bptr,
                                const float* __restrict__ ws,
                                float* __restrict__ out) {
    float e_ij = leaky(ws[1] + ws[2] + bptr[0]);
    out[0] = e_ij / ws[0];
}

extern "C" void kernel_launch(void* const* d_in, const int* in_sizes, int n_in,
                              void* d_out, int out_size, void* d_ws, size_t ws_size,
                              hipStream_t stream) {
    const int*   g = (const int*)d_in[0];    // (E,2) int32
    const float* h = (const float*)d_in[1];  // (N,128) f32
    const int*   ip = (const int*)d_in[2];   // scalar i
    const int*   jp = (const int*)d_in[3];   // scalar j
    const float* W = (const float*)d_in[4];  // (1,256) f32
    const float* b = (const float*)d_in[5];  // (1,) f32
    float* out = (float*)d_out;
    float* ws = (float*)d_ws;

    long long E = (long long)in_sizes[0] / 2;
    long long npairs = E / 2;
    long long nthreads = npairs + (E & 1);  // +1 thread for odd tail
    int block = 256;
    long long grid = (nthreads + block - 1) / block;

    precompute_kernel<<<1, 64, 0, stream>>>(h, W, ip, jp, ws);
    scan_edges_kernel<<<(int)grid, block, 0, stream>>>(
        (const int4*)g, npairs, g, E, h, W, ip, b, ws);
    finalize_kernel<<<1, 1, 0, stream>>>(b, ws, out);
}